// Round 1
// baseline (439.448 us; speedup 1.0000x reference)
//
#include <hip/hip_runtime.h>

// PillarMaxPooling: fused Linear(10->64, no bias) -> BN1d(eval, eps=1e-3) -> ReLU
// -> segment_max into pillars, empty pillars -> 0.
//
// Strategy:
//  - out zero-initialized via hipMemsetAsync; ReLU output >= 0 so segment_max
//    == atomicMax on the unsigned bit pattern (monotone for non-negative floats),
//    and the zero init also realizes maximum(pooled, 0) / empty-pillar = 0.
//  - one wave handles 6 points per iteration: lanes 0..59 make one coalesced
//    240B load of x; per point the 10 x values are broadcast with v_readlane
//    (VALU pipe, no LDS traffic); lane c owns output channel c with W[:,c] and
//    folded BN scale/bias in registers; 10 FMAs + 1 atomicMax per lane.

#define C_IN  10
#define C_OUT 64
#define PPI   6          // points per wave-iteration (6*10 = 60 lanes load x)
#define BLOCK 256
#define GRID  2048       // 8192 waves = full occupancy target

__device__ __forceinline__ float bcast(float v, int srclane) {
    return __int_as_float(__builtin_amdgcn_readlane(__float_as_int(v), srclane));
}

__global__ __launch_bounds__(BLOCK)
void pillar_fused_kernel(const float* __restrict__ gf,
                         const int*   __restrict__ idx,
                         const float* __restrict__ W,
                         const float* __restrict__ gamma,
                         const float* __restrict__ beta,
                         const float* __restrict__ rmean,
                         const float* __restrict__ rvar,
                         float*       __restrict__ out,
                         int P)
{
    const int lane   = threadIdx.x & 63;
    const int waveId = blockIdx.x * (BLOCK >> 6) + (threadIdx.x >> 6);
    const int nWaves = GRID * (BLOCK >> 6);

    // Per-lane channel parameters (lane == output channel).
    float w[C_IN];
#pragma unroll
    for (int k = 0; k < C_IN; ++k) w[k] = W[k * C_OUT + lane];
    const float inv_std = gamma[lane] * rsqrtf(rvar[lane] + 1e-3f);
    const float bias    = fmaf(-rmean[lane], inv_std, beta[lane]);

    const int nGroups = (P + PPI - 1) / PPI;
    for (int g = waveId; g < nGroups; g += nWaves) {
        const int p0 = g * PPI;

        // Coalesced feature load: lanes 0..59 cover 6 points x 10 feats.
        float xv = 0.0f;
        {
            const int e = p0 * C_IN + lane;
            if (lane < C_IN * PPI && e < P * C_IN) xv = gf[e];
        }
        // Pillar indices for the 6 points: lanes 0..5.
        int iv = 0;
        if (lane < PPI && (p0 + lane) < P) iv = idx[p0 + lane];

#pragma unroll
        for (int j = 0; j < PPI; ++j) {
            if (p0 + j >= P) break;                 // wave-uniform tail guard
            float acc = 0.0f;
#pragma unroll
            for (int k = 0; k < C_IN; ++k)
                acc = fmaf(bcast(xv, j * C_IN + k), w[k], acc);
            const float h = fmaxf(fmaf(acc, inv_std, bias), 0.0f);
            const int   m = __builtin_amdgcn_readlane(iv, j);
            atomicMax((unsigned int*)(out + m * C_OUT + lane),
                      __float_as_uint(h));
        }
    }
}

extern "C" void kernel_launch(void* const* d_in, const int* in_sizes, int n_in,
                              void* d_out, int out_size, void* d_ws, size_t ws_size,
                              hipStream_t stream) {
    const float* gf    = (const float*)d_in[0];
    const int*   idx   = (const int*)  d_in[1];
    // d_in[2] = num_pillars (device scalar) — M derived from out_size instead.
    const float* W     = (const float*)d_in[3];
    const float* gamma = (const float*)d_in[4];
    const float* beta  = (const float*)d_in[5];
    const float* rmean = (const float*)d_in[6];
    const float* rvar  = (const float*)d_in[7];
    float*       out   = (float*)d_out;

    const int P = in_sizes[0] / C_IN;

    // Zero-init output: identity for the bitwise atomicMax AND the final
    // maximum(pooled, 0) / empty-pillar semantics.
    hipMemsetAsync(out, 0, (size_t)out_size * sizeof(float), stream);

    pillar_fused_kernel<<<GRID, BLOCK, 0, stream>>>(gf, idx, W, gamma, beta,
                                                    rmean, rvar, out, P);
}